// Round 1
// baseline (213.352 us; speedup 1.0000x reference)
//
#include <hip/hip_runtime.h>
#include <hip/hip_bf16.h>
#include <cstddef>

// Problem constants (B,S,D,E,K = 4,4096,2048,64,2)
namespace {
constexpr int kB = 4;
constexpr int kS = 4096;
constexpr int kD = 2048;
constexpr int kE = 64;
constexpr int kN = kB * kS;               // 16384 tokens
constexpr int kTokPerBlk = 64;            // tokens per block (= lanes per wave)
constexpr int kBlocks = kN / kTokPerBlk;  // 256 blocks
constexpr int kThreads = 512;             // 8 waves: 4 expert-groups x 2 D-halves
constexpr int kDHalf = kD / 2;            // 1024
constexpr int kEG = 16;                   // experts per group
}

// ---------------------------------------------------------------------------
// Kernel 0: zero the workspace accumulators (ws is poisoned 0xAA once and we
// accumulate with atomics each call -> must reset every launch).
__global__ void zero_ws_kernel(float* __restrict__ ws) {
  if (threadIdx.x < 256) ws[threadIdx.x] = 0.0f;
}

// ---------------------------------------------------------------------------
// Kernel 1: per-token logits (fp32), softmax, top-2, output tensors, loss
// partials. Block = 64 tokens, 512 threads = 8 waves.
//   wave w: expert-group eg = w & 3 (16 experts), d-half dh = w >> 2 (1024 d)
//   lane   = token within block
// W reads are wave-uniform -> scalar loads (s_load) on the scalar pipe.
__global__ __launch_bounds__(kThreads)
void moe_gate_kernel(const float* __restrict__ x, const float* __restrict__ W,
                     float* __restrict__ out, float* __restrict__ ws) {
  // Padded LDS to stay bank-conflict free (strides 17 / 65 are coprime to 32).
  __shared__ float red[4][kTokPerBlk][kEG + 1];   // dh==1 partials, 17.4 KB
  __shared__ float lg[kTokPerBlk][kE + 1];        // reduced logits, 16.6 KB
  __shared__ int ti0[kTokPerBlk];
  __shared__ int ti1[kTokPerBlk];
  __shared__ float tv0[kTokPerBlk];
  __shared__ float tv1[kTokPerBlk];
  __shared__ float tz2[kTokPerBlk];

  const int tid = threadIdx.x;
  const int lane = tid & 63;
  const int wv = __builtin_amdgcn_readfirstlane(tid >> 6);  // wave id, uniform
  const int eg = wv & 3;
  const int dh = wv >> 2;
  const int tok0 = blockIdx.x * kTokPerBlk;
  const int token = tok0 + lane;

  const float* __restrict__ xrow = x + (size_t)token * kD + dh * kDHalf;
  const float* __restrict__ wb = W + (size_t)(eg * kEG) * kD + dh * kDHalf;

  float2 acc[kEG];
#pragma unroll
  for (int e = 0; e < kEG; ++e) acc[e] = make_float2(0.0f, 0.0f);

  for (int d0 = 0; d0 < kDHalf; d0 += 8) {
    const float4 xa = *reinterpret_cast<const float4*>(xrow + d0);
    const float4 xb = *reinterpret_cast<const float4*>(xrow + d0 + 4);
#pragma unroll
    for (int e = 0; e < kEG; ++e) {
      const float* __restrict__ w = wb + e * kD + d0;  // uniform -> s_load
      acc[e].x = fmaf(xa.x, w[0], acc[e].x);
      acc[e].y = fmaf(xa.y, w[1], acc[e].y);
      acc[e].x = fmaf(xa.z, w[2], acc[e].x);
      acc[e].y = fmaf(xa.w, w[3], acc[e].y);
      acc[e].x = fmaf(xb.x, w[4], acc[e].x);
      acc[e].y = fmaf(xb.y, w[5], acc[e].y);
      acc[e].x = fmaf(xb.z, w[6], acc[e].x);
      acc[e].y = fmaf(xb.w, w[7], acc[e].y);
    }
  }

  // Reduce the two D-halves through LDS (deterministic, conflict-free).
  if (dh == 1) {
#pragma unroll
    for (int e = 0; e < kEG; ++e) red[eg][lane][e] = acc[e].x + acc[e].y;
  }
  __syncthreads();
  if (dh == 0) {
#pragma unroll
    for (int e = 0; e < kEG; ++e)
      lg[lane][eg * kEG + e] = acc[e].x + acc[e].y + red[eg][lane][e];
  }
  __syncthreads();

  // --- softmax + top-2 + z-loss: wave 0, thread = token -------------------
  if (tid < kTokPerBlk) {
    float v0 = -INFINITY, v1 = -INFINITY;
    int i0 = 0, i1 = 0;
    for (int e = 0; e < kE; ++e) {
      const float l = lg[tid][e];
      if (l > v0) { v1 = v0; i1 = i0; v0 = l; i0 = e; }
      else if (l > v1) { v1 = l; i1 = e; }
    }
    const float m = v0;  // row max
    float s = 0.0f;
    for (int e = 0; e < kE; ++e) s += __expf(lg[tid][e] - m);
    const float rs = 1.0f / s;
    // z-loss uses logsumexp over the *softmaxed* probs (reference quirk).
    float zexp = 0.0f;
    for (int e = 0; e < kE; ++e) {
      const float p = __expf(lg[tid][e] - m) * rs;
      zexp += __expf(p);
    }
    const float z = logf(zexp);
    ti0[tid] = i0;
    ti1[tid] = i1;
    tv0[tid] = rs;                    // exp(v0-m)*rs with v0==m
    tv1[tid] = __expf(v1 - m) * rs;
    tz2[tid] = z * z;
  }
  __syncthreads();

  // --- loss partials: thread = expert (deterministic in-block order) ------
  if (tid < kE) {
    const int e = tid;
    float g = 0.0f, c = 0.0f;
    for (int t = 0; t < kTokPerBlk; ++t) {
      if (ti0[t] == e) { g += tv0[t]; c += 1.0f; }
      if (ti1[t] == e) { g += tv1[t]; c += 1.0f; }
    }
    atomicAdd(&ws[e], g);
    atomicAdd(&ws[kE + e], c);
    // z^2 sum across the block's 64 tokens (wave 0 butterfly).
    float z2 = tz2[tid];
    for (int off = 32; off; off >>= 1) z2 += __shfl_down(z2, off);
    if (tid == 0) atomicAdd(&ws[2 * kE], z2);
  }

  // --- write dispatch/combine tensors: all 512 threads, coalesced float4 --
  // Layout: [n][e][k], K=2 -> per token 128 floats = 32 float4.
  {
    const int t = tid >> 3;    // token in block (64)
    const int sub = tid & 7;   // 8 threads per token
    const int tok = tok0 + t;
    const int i0 = ti0[t], i1 = ti1[t];
    const float v0 = tv0[t], v1 = tv1[t];
    float4* __restrict__ dptr = reinterpret_cast<float4*>(out) + (size_t)tok * 32;
    float4* __restrict__ cptr =
        reinterpret_cast<float4*>(out) + (size_t)kN * 32 + (size_t)tok * 32;
#pragma unroll
    for (int q4 = 0; q4 < 4; ++q4) {
      const int q = sub * 4 + q4;   // float4 index within token
      const int e0 = q * 2, e1 = q * 2 + 1;
      const float d0v = (e0 == i0 || e0 == i1) ? 1.0f : 0.0f;
      const float d1v = (e1 == i0 || e1 == i1) ? 1.0f : 0.0f;
      const float c0 = (e0 == i0) ? v0 : ((e0 == i1) ? v1 : 0.0f);
      const float c1 = (e1 == i0) ? v0 : ((e1 == i1) ? v1 : 0.0f);
      dptr[q] = make_float4(d0v, 0.0f, d1v, 0.0f);
      cptr[q] = make_float4(c0, 0.0f, c1, 0.0f);
    }
  }
}

// ---------------------------------------------------------------------------
// Kernel 2: finalize scalar losses.
__global__ void finalize_kernel(const float* __restrict__ ws,
                                float* __restrict__ out) {
  const int e = threadIdx.x;  // 64 threads
  float prod = ws[e] * ws[kE + e];
  for (int off = 32; off; off >>= 1) prod += __shfl_down(prod, off);
  if (e == 0) {
    const size_t base = (size_t)2 * kN * kE * 2;  // after dispatch+combine
    const float invN = 1.0f / (float)kN;
    out[base] = prod * ((float)kE * invN * invN);   // load_balancing_loss
    out[base + 1] = ws[2 * kE] * invN;              // router_z_loss
  }
}

// ---------------------------------------------------------------------------
extern "C" void kernel_launch(void* const* d_in, const int* in_sizes, int n_in,
                              void* d_out, int out_size, void* d_ws,
                              size_t ws_size, hipStream_t stream) {
  const float* x = (const float*)d_in[0];   // [4,4096,2048] fp32
  const float* W = (const float*)d_in[1];   // [64,2048] fp32
  float* out = (float*)d_out;               // dispatch | combine | lbl | z
  float* ws = (float*)d_ws;

  zero_ws_kernel<<<1, 256, 0, stream>>>(ws);
  moe_gate_kernel<<<kBlocks, kThreads, 0, stream>>>(x, W, out, ws);
  finalize_kernel<<<1, kE, 0, stream>>>(ws, out);
}